// Round 2
// baseline (1669.715 us; speedup 1.0000x reference)
//
#include <hip/hip_runtime.h>

#define BB 32
#define TT 2048
#define DD 256
#define HH 256
#define AA 128
#define CC 4367
#define CLS_LD 4480   // 35*128, padded WclsT leading dim
#define CLS_KP 32     // cls k-panel staged in LDS
#define NSTEPS 22
#define NCHUNK 32     // att t-chunks (64 t each)

typedef unsigned short ushortT;
typedef unsigned int uintT;
using frag8 = __attribute__((ext_vector_type(8))) short;
using f32x4 = __attribute__((ext_vector_type(4))) float;

__device__ __forceinline__ float tanh_fast(float u) {
  float e = __expf(2.0f * u);
  return 1.0f - 2.0f / (e + 1.0f);
}
__device__ __forceinline__ float sigmoid_fast(float u) {
  return 1.0f / (1.0f + __expf(-u));
}
__device__ __forceinline__ ushortT f2bf(float f) {
  unsigned int u = __float_as_uint(f);
  unsigned int r = (u + 0x7FFFu + ((u >> 16) & 1u)) >> 16;
  return (ushortT)r;
}
__device__ __forceinline__ float bf2f(ushortT v) {
  return __uint_as_float(((unsigned int)v) << 16);
}

// ---------- prep: WclsT fp32 [256][4480] and WxT_bf bf16 [128][256] ----------
__global__ __launch_bounds__(256) void trans_kernel(
    const float* __restrict__ Wx, const float* __restrict__ W_cls,
    float* __restrict__ WclsT, ushortT* __restrict__ WxT_bf) {
  int blk = blockIdx.x;
  __shared__ float tile[32][33];
  const int li = threadIdx.x >> 5, lj = threadIdx.x & 31;
  if (blk < 1096) {  // W_cls 4367x256 -> WclsT 256x4480
    int i0 = (blk >> 3) * 32, j0 = (blk & 7) * 32;
#pragma unroll
    for (int k = 0; k < 4; ++k) {
      int i = i0 + li + k * 8;
      if (i < CC) tile[li + k * 8][lj] = W_cls[(size_t)i * 256 + j0 + lj];
    }
    __syncthreads();
#pragma unroll
    for (int k = 0; k < 4; ++k) {
      int j = j0 + li + k * 8, i = i0 + lj;
      if (i < CC) WclsT[(size_t)j * CLS_LD + i] = tile[lj][li + k * 8];
    }
  } else {  // Wx 256x128 -> WxT_bf 128x256
    blk -= 1096;  // 0..31
    int i0 = (blk >> 2) * 32, j0 = (blk & 3) * 32;
#pragma unroll
    for (int k = 0; k < 4; ++k)
      tile[li + k * 8][lj] = Wx[(size_t)(i0 + li + k * 8) * 128 + j0 + lj];
    __syncthreads();
#pragma unroll
    for (int k = 0; k < 4; ++k) {
      int j = j0 + li + k * 8;
      WxT_bf[(size_t)j * 256 + i0 + lj] = f2bf(tile[lj][li + k * 8]);
    }
  }
}

// ---------- xW via MFMA bf16: block = 128 rows of [BT,256] x [256,128] ----------
__global__ __launch_bounds__(256) void xw_mfma(
    const float* __restrict__ x, const ushortT* __restrict__ WxT_bf,
    ushortT* __restrict__ x_bf, ushortT* __restrict__ xWT) {
  __shared__ ushortT lds[2 * 128 * 72];  // sX | sW staging; reused as sT[128][136]
#define SX(r, c) lds[(r) * 72 + (c)]
#define SW(r, c) lds[128 * 72 + (r) * 72 + (c)]
#define ST(a, m) lds[(a) * 136 + (m)]
  const int tid = threadIdx.x;
  const int lane = tid & 63, w = tid >> 6;
  const int l15 = lane & 15, quad = lane >> 4;
  const int r0 = blockIdx.x * 128;
  const int bb = blockIdx.x >> 4, t0 = (blockIdx.x & 15) * 128;
  const int row = tid >> 1, half = tid & 1;

  f32x4 acc[2][8];
#pragma unroll
  for (int mt = 0; mt < 2; ++mt)
#pragma unroll
    for (int nt = 0; nt < 8; ++nt) acc[mt][nt] = (f32x4){0.f, 0.f, 0.f, 0.f};

  for (int kk0 = 0; kk0 < 256; kk0 += 64) {
    // stage x (fp32 -> bf16) + write-through to x_bf
    {
      const float4* xp = (const float4*)(x + (size_t)(r0 + row) * DD + kk0 + half * 32);
      uint4 pk[4];
#pragma unroll
      for (int i = 0; i < 4; ++i) {
        float4 f0 = xp[2 * i], f1 = xp[2 * i + 1];
        pk[i].x = (uintT)f2bf(f0.x) | ((uintT)f2bf(f0.y) << 16);
        pk[i].y = (uintT)f2bf(f0.z) | ((uintT)f2bf(f0.w) << 16);
        pk[i].z = (uintT)f2bf(f1.x) | ((uintT)f2bf(f1.y) << 16);
        pk[i].w = (uintT)f2bf(f1.z) | ((uintT)f2bf(f1.w) << 16);
      }
      uint4* sxp = (uint4*)&SX(row, half * 32);
      uint4* gxp = (uint4*)(x_bf + (size_t)(r0 + row) * DD + kk0 + half * 32);
#pragma unroll
      for (int i = 0; i < 4; ++i) { sxp[i] = pk[i]; gxp[i] = pk[i]; }
    }
    // stage WxT_bf slice (n=row)
    {
      const uint4* wp = (const uint4*)(WxT_bf + (size_t)row * DD + kk0 + half * 32);
      uint4* swp = (uint4*)&SW(row, half * 32);
#pragma unroll
      for (int i = 0; i < 4; ++i) swp[i] = wp[i];
    }
    __syncthreads();
#pragma unroll
    for (int kk = 0; kk < 2; ++kk) {
      frag8 a0 = *(const frag8*)&SX(w * 32 + l15, kk * 32 + quad * 8);
      frag8 a1 = *(const frag8*)&SX(w * 32 + 16 + l15, kk * 32 + quad * 8);
#pragma unroll
      for (int nt = 0; nt < 8; ++nt) {
        frag8 bf = *(const frag8*)&SW(nt * 16 + l15, kk * 32 + quad * 8);
        acc[0][nt] = __builtin_amdgcn_mfma_f32_16x16x32_bf16(a0, bf, acc[0][nt], 0, 0, 0);
        acc[1][nt] = __builtin_amdgcn_mfma_f32_16x16x32_bf16(a1, bf, acc[1][nt], 0, 0, 0);
      }
    }
    __syncthreads();
  }
  // transpose-bounce: sT[a][m] = D[m][a], then write xWT[b][a][t0+m]
#pragma unroll
  for (int mt = 0; mt < 2; ++mt)
#pragma unroll
    for (int nt = 0; nt < 8; ++nt)
#pragma unroll
      for (int r = 0; r < 4; ++r) {
        int m = w * 32 + mt * 16 + quad * 4 + r;
        int a = nt * 16 + l15;
        ST(a, m) = f2bf(acc[mt][nt][r]);
      }
  __syncthreads();
  {
    const uint4* sp = (const uint4*)&ST(row, half * 64);
    uint4* gp = (uint4*)(xWT + ((size_t)bb * AA + row) * TT + t0 + half * 64);
#pragma unroll
    for (int i = 0; i < 8; ++i) gp[i] = sp[i];
  }
#undef SX
#undef SW
#undef ST
}

// ---------- fused GRU step: ctx/den reduce + gates + h-combine + hWh ----------
// grid 32 (one block per b), 256 thr. Thread tid owns gate rows {tid, 256+tid,
// 512+tid} of both W_ih and W_hh as full-length dots (row-per-lane; one gate
// pair at a time keeps the L1 working set at 16 KB, 8x line reuse), so the
// r/z/n pre-activations for hidden element tid end up in this thread's
// registers -> h-combine needs no shuffles and no intermediate buffers.
__global__ __launch_bounds__(256) void gru_kernel(
    const float* __restrict__ ctx_part, const float* __restrict__ den_part,
    const float* __restrict__ W_ih, const float* __restrict__ W_hh,
    const float* __restrict__ b_ih, const float* __restrict__ b_hh,
    const float* __restrict__ Wh, float* __restrict__ hall,
    float* __restrict__ hWh_buf, int s) {
  const int b = blockIdx.x, tid = threadIdx.x;
  __shared__ __align__(16) float sctx[DD];
  __shared__ __align__(16) float sh_prev[HH];
  __shared__ __align__(16) float sh[HH];
  __shared__ float part[2][AA];
  __shared__ float sden;
  if (tid < 32) {  // den partial reduce (one wave)
    float d = den_part[b * NCHUNK + tid];
#pragma unroll
    for (int off = 16; off > 0; off >>= 1) d += __shfl_down(d, off, 32);
    if (tid == 0) sden = d;
  }
  {  // ctx partial reduce: coalesced (256 lanes x 32 chunks), keep unscaled
    float acc = 0.f;
#pragma unroll
    for (int c = 0; c < NCHUNK; ++c)
      acc += ctx_part[((size_t)b * NCHUNK + c) * DD + tid];
    sctx[tid] = acc;
  }
  sh_prev[tid] = (s >= 2) ? hall[((size_t)(s - 2) * BB + b) * HH + tid] : 0.f;
  __syncthreads();
  const float invd = 1.0f / sden;
  const float4* sctx4 = (const float4*)sctx;
  const float4* shp4 = (const float4*)sh_prev;
  float gi_g[3], gh_g[3];
#pragma unroll
  for (int gg = 0; gg < 3; ++gg) {
    const float4* wi = (const float4*)(W_ih + (size_t)(gg * 256 + tid) * DD);
    const float4* wh = (const float4*)(W_hh + (size_t)(gg * 256 + tid) * HH);
    float ix = 0.f, iy = 0.f, iz = 0.f, iw = 0.f;
    float hx = 0.f, hy = 0.f, hz = 0.f, hw = 0.f;
#pragma unroll 8
    for (int k4 = 0; k4 < DD / 4; ++k4) {
      float4 wv = wi[k4], cv = sctx4[k4];
      ix = fmaf(cv.x, wv.x, ix); iy = fmaf(cv.y, wv.y, iy);
      iz = fmaf(cv.z, wv.z, iz); iw = fmaf(cv.w, wv.w, iw);
      float4 wv2 = wh[k4], hv4 = shp4[k4];
      hx = fmaf(hv4.x, wv2.x, hx); hy = fmaf(hv4.y, wv2.y, hy);
      hz = fmaf(hv4.z, wv2.z, hz); hw = fmaf(hv4.w, wv2.w, hw);
    }
    gi_g[gg] = (ix + iy) + (iz + iw);
    gh_g[gg] = (hx + hy) + (hz + hw);
  }
  // h-combine: everything for element tid is already local
  {
    float gir = gi_g[0] * invd + b_ih[tid];
    float giz = gi_g[1] * invd + b_ih[256 + tid];
    float gin = gi_g[2] * invd + b_ih[512 + tid];
    float ghr = gh_g[0] + b_hh[tid];
    float ghz = gh_g[1] + b_hh[256 + tid];
    float ghn = gh_g[2] + b_hh[512 + tid];
    float r = sigmoid_fast(gir + ghr);
    float z = sigmoid_fast(giz + ghz);
    float n = tanh_fast(gin + r * ghn);
    float hv = (1.f - z) * n + z * sh_prev[tid];
    hall[((size_t)(s - 1) * BB + b) * HH + tid] = hv;
    sh[tid] = hv;
  }
  __syncthreads();
  // hWh: 128 a x 2-way k-split
  {
    const int a = tid & 127, kh = tid >> 7;
    float acc = 0.f;
#pragma unroll 8
    for (int k = kh * 128; k < kh * 128 + 128; ++k)
      acc = fmaf(sh[k], Wh[k * AA + a], acc);
    part[kh][a] = acc;
  }
  __syncthreads();
  if (tid < AA) hWh_buf[b * AA + tid] = part[0][tid] + part[1][tid];
}

// ---------- per-step attention. grid (32 chunks, 32 b), 256 thr ----------
__global__ __launch_bounds__(256, 4) void att_kernel(
    const ushortT* __restrict__ x_bf, const ushortT* __restrict__ xWT_bf,
    const float* __restrict__ hWh_buf, const float* __restrict__ v,
    float* __restrict__ ctx_part, float* __restrict__ den_part) {
  const int tid = threadIdx.x;
  const int chunk = blockIdx.x;  // 0..31, 64 t's each
  const int b = blockIdx.y;
  const int t0 = chunk * 64;
  __shared__ float sh_hWh[AA], sh_v[AA];
  __shared__ float sh_part[8 * 64];
  __shared__ float sh_w[64];
  __shared__ __align__(16) float sh_ctx[4 * DD];
  if (tid < AA) {
    sh_hWh[tid] = hWh_buf ? hWh_buf[b * AA + tid] : 0.f;
    sh_v[tid] = v[tid];
  }
  // Prefetch Phase-B x into regs (independent of scores) so all loads overlap
  const int j4 = tid >> 6, dq = tid & 63;
  ushort4 xr[16];
  {
    const ushort4* xb4 = (const ushort4*)x_bf;
#pragma unroll
    for (int j = 0; j < 16; ++j)
      xr[j] = xb4[(((size_t)(b * TT + t0 + j * 4 + j4)) * DD >> 2) + dq];
  }
  __syncthreads();
  // Phase A: scores. thread = (q = a-group of 16, tp = t-pair)
  {
    const int q = tid >> 5, tp = tid & 31;
    float p0 = 0.f, p1 = 0.f;
    const ushort2* xw2 = (const ushort2*)xWT_bf;
    const size_t base = (size_t)b * (AA * TT / 2) + (t0 >> 1) + tp;
#pragma unroll
    for (int i = 0; i < 16; ++i) {
      int a = q * 16 + i;
      ushort2 u = xw2[base + (size_t)a * (TT / 2)];
      float hwa = sh_hWh[a], va = sh_v[a];
      p0 = fmaf(tanh_fast(bf2f(u.x) + hwa), va, p0);
      p1 = fmaf(tanh_fast(bf2f(u.y) + hwa), va, p1);
    }
    sh_part[q * 64 + 2 * tp] = p0;
    sh_part[q * 64 + 2 * tp + 1] = p1;
  }
  __syncthreads();
  if (tid < 64) {
    float e = 0.f;
#pragma unroll
    for (int q = 0; q < 8; ++q) e += sh_part[q * 64 + tid];
    sh_w[tid] = __expf(e);  // |e| <= ||v||_1 ~ 5: no overflow, no max-pass
  }
  __syncthreads();
  // Phase B: ctx partials from prefetched regs
  {
    float4 acc = {0.f, 0.f, 0.f, 0.f};
#pragma unroll
    for (int j = 0; j < 16; ++j) {
      float w = sh_w[j * 4 + j4];
      acc.x = fmaf(w, bf2f(xr[j].x), acc.x);
      acc.y = fmaf(w, bf2f(xr[j].y), acc.y);
      acc.z = fmaf(w, bf2f(xr[j].z), acc.z);
      acc.w = fmaf(w, bf2f(xr[j].w), acc.w);
    }
    ((float4*)sh_ctx)[j4 * 64 + dq] = acc;
  }
  __syncthreads();
  {
    float sum = sh_ctx[tid] + sh_ctx[DD + tid] + sh_ctx[2 * DD + tid] + sh_ctx[3 * DD + tid];
    ctx_part[((size_t)b * NCHUNK + chunk) * DD + tid] = sum;  // plain coalesced store
  }
  if (tid < 64) {
    float ds = sh_w[tid];
#pragma unroll
    for (int off = 32; off > 0; off >>= 1) ds += __shfl_down(ds, off, 64);
    if (tid == 0) den_part[b * NCHUNK + chunk] = ds;
  }
}

// ---------- final: out[b,s,c] = hall[s,b,:] @ W_cls^T + b_cls ----------
// LDS-staged WclsT k-panels: kills the 8x redundant L2 reads (one per rg group).
__global__ __launch_bounds__(256) void cls_kernel(
    const float* __restrict__ hall, const float* __restrict__ WclsT,
    const float* __restrict__ b_cls, float* __restrict__ out) {
  const int tid = threadIdx.x;
  const int c0 = blockIdx.x * 128;
  const int r0 = blockIdx.y * 32;
  const int cq = tid & 31, rg = tid >> 5;
  const int c = c0 + cq * 4;
  __shared__ __align__(16) float shh[32 * HH];        // 32 KB: h rows
  __shared__ __align__(16) float sW[CLS_KP][128];     // 16 KB: WclsT k-panel
  {
    const float4* hsrc = (const float4*)(hall + (size_t)r0 * HH);
    float4* hdst = (float4*)shh;
#pragma unroll
    for (int i = 0; i < 8; ++i) hdst[tid + 256 * i] = hsrc[tid + 256 * i];
  }
  float acc[4][4];
#pragma unroll
  for (int j = 0; j < 4; ++j)
#pragma unroll
    for (int l = 0; l < 4; ++l) acc[j][l] = 0.f;
  for (int k0 = 0; k0 < HH; k0 += CLS_KP) {
    __syncthreads();  // prev compute done (and h staged, first iter)
    {   // stage 32k x 128c panel, coalesced, each element once
      const int tk = tid >> 5, tc = tid & 31;
#pragma unroll
      for (int kk = 0; kk < 4; ++kk) {
        int k = tk * 4 + kk;
        ((float4*)&sW[k][0])[tc] =
            *(const float4*)(WclsT + (size_t)(k0 + k) * CLS_LD + c0 + tc * 4);
      }
    }
    __syncthreads();
#pragma unroll
    for (int k4 = 0; k4 < CLS_KP / 4; ++k4) {
      float4 w0 = ((const float4*)&sW[k4 * 4 + 0][0])[cq];
      float4 w1 = ((const float4*)&sW[k4 * 4 + 1][0])[cq];
      float4 w2 = ((const float4*)&sW[k4 * 4 + 2][0])[cq];
      float4 w3 = ((const float4*)&sW[k4 * 4 + 3][0])[cq];
#pragma unroll
      for (int j = 0; j < 4; ++j) {
        float4 h4v = *(const float4*)&shh[(rg * 4 + j) * HH + k0 + k4 * 4];
        acc[j][0] = fmaf(h4v.x, w0.x, acc[j][0]); acc[j][1] = fmaf(h4v.x, w0.y, acc[j][1]);
        acc[j][2] = fmaf(h4v.x, w0.z, acc[j][2]); acc[j][3] = fmaf(h4v.x, w0.w, acc[j][3]);
        acc[j][0] = fmaf(h4v.y, w1.x, acc[j][0]); acc[j][1] = fmaf(h4v.y, w1.y, acc[j][1]);
        acc[j][2] = fmaf(h4v.y, w1.z, acc[j][2]); acc[j][3] = fmaf(h4v.y, w1.w, acc[j][3]);
        acc[j][0] = fmaf(h4v.z, w2.x, acc[j][0]); acc[j][1] = fmaf(h4v.z, w2.y, acc[j][1]);
        acc[j][2] = fmaf(h4v.z, w2.z, acc[j][2]); acc[j][3] = fmaf(h4v.z, w2.w, acc[j][3]);
        acc[j][0] = fmaf(h4v.w, w3.x, acc[j][0]); acc[j][1] = fmaf(h4v.w, w3.y, acc[j][1]);
        acc[j][2] = fmaf(h4v.w, w3.z, acc[j][2]); acc[j][3] = fmaf(h4v.w, w3.w, acc[j][3]);
      }
    }
  }
#pragma unroll
  for (int j = 0; j < 4; ++j) {
    int row = r0 + rg * 4 + j;  // row = s*BB + b
    int bb = row & (BB - 1), st = row >> 5;
    size_t obase = ((size_t)bb * NSTEPS + st) * CC;
#pragma unroll
    for (int l = 0; l < 4; ++l) {
      int cc = c + l;
      if (cc < CC) out[obase + cc] = acc[j][l] + b_cls[cc];
    }
  }
}

extern "C" void kernel_launch(void* const* d_in, const int* in_sizes, int n_in,
                              void* d_out, int out_size, void* d_ws, size_t ws_size,
                              hipStream_t stream) {
  const float* x     = (const float*)d_in[0];
  const float* Wx    = (const float*)d_in[1];
  const float* Wh    = (const float*)d_in[2];
  const float* v     = (const float*)d_in[3];
  const float* W_ih  = (const float*)d_in[4];
  const float* W_hh  = (const float*)d_in[5];
  const float* b_ih  = (const float*)d_in[6];
  const float* b_hh  = (const float*)d_in[7];
  const float* W_cls = (const float*)d_in[8];
  const float* b_cls = (const float*)d_in[9];
  float* out = (float*)d_out;

  // workspace
  float* ctx_part = (float*)d_ws;                           // 32*32*256
  float* den_part = ctx_part + (size_t)BB * NCHUNK * DD;    // 32*32
  float* hWh_buf  = den_part + BB * NCHUNK;                 // 32*128
  float* hall     = hWh_buf + BB * AA;                      // 22*32*256
  float* WclsT    = hall + (size_t)NSTEPS * BB * HH;        // 256*4480
  ushortT* WxT_bf = (ushortT*)(WclsT + (size_t)256 * CLS_LD);  // 128*256
  ushortT* x_bf   = WxT_bf + 128 * 256;                     // BT*256
  ushortT* xWT    = x_bf + (size_t)BB * TT * DD;            // B*A*T

  trans_kernel<<<1096 + 32, 256, 0, stream>>>(Wx, W_cls, WclsT, WxT_bf);
  xw_mfma<<<(BB * TT) / 128, 256, 0, stream>>>(x, WxT_bf, x_bf, xWT);

  att_kernel<<<dim3(NCHUNK, BB), 256, 0, stream>>>(x_bf, xWT, nullptr, v, ctx_part, den_part);
  for (int s = 1; s < NSTEPS; ++s) {
    gru_kernel<<<BB, 256, 0, stream>>>(ctx_part, den_part, W_ih, W_hh,
                                       b_ih, b_hh, Wh, hall, hWh_buf, s);
    att_kernel<<<dim3(NCHUNK, BB), 256, 0, stream>>>(x_bf, xWT, hWh_buf, v, ctx_part, den_part);
  }
  gru_kernel<<<BB, 256, 0, stream>>>(ctx_part, den_part, W_ih, W_hh,
                                     b_ih, b_hh, Wh, hall, hWh_buf, NSTEPS);
  cls_kernel<<<dim3(35, 22), 256, 0, stream>>>(hall, WclsT, b_cls, out);
}

// Round 3
// 1260.019 us; speedup vs baseline: 1.3252x; 1.3252x over previous
//
#include <hip/hip_runtime.h>

#define BB 32
#define TT 2048
#define DD 256
#define HH 256
#define AA 128
#define CC 4367
#define CLS_LD 4480   // 35*128, padded WclsT leading dim
#define CLS_KP 32     // cls k-panel staged in LDS
#define NSTEPS 22
#define NCHUNK 32     // att t-chunks (64 t each)

typedef unsigned short ushortT;
typedef unsigned int uintT;
using frag8 = __attribute__((ext_vector_type(8))) short;
using f32x4 = __attribute__((ext_vector_type(4))) float;

__device__ __forceinline__ float tanh_fast(float u) {
  float e = __expf(2.0f * u);
  return 1.0f - 2.0f / (e + 1.0f);
}
__device__ __forceinline__ float sigmoid_fast(float u) {
  return 1.0f / (1.0f + __expf(-u));
}
__device__ __forceinline__ ushortT f2bf(float f) {
  unsigned int u = __float_as_uint(f);
  unsigned int r = (u + 0x7FFFu + ((u >> 16) & 1u)) >> 16;
  return (ushortT)r;
}
__device__ __forceinline__ float bf2f(ushortT v) {
  return __uint_as_float(((unsigned int)v) << 16);
}

// ---------- prep: WclsT fp32 [256][4480] and WxT_bf bf16 [128][256] ----------
__global__ __launch_bounds__(256) void trans_kernel(
    const float* __restrict__ Wx, const float* __restrict__ W_cls,
    float* __restrict__ WclsT, ushortT* __restrict__ WxT_bf) {
  int blk = blockIdx.x;
  __shared__ float tile[32][33];
  const int li = threadIdx.x >> 5, lj = threadIdx.x & 31;
  if (blk < 1096) {  // W_cls 4367x256 -> WclsT 256x4480
    int i0 = (blk >> 3) * 32, j0 = (blk & 7) * 32;
#pragma unroll
    for (int k = 0; k < 4; ++k) {
      int i = i0 + li + k * 8;
      if (i < CC) tile[li + k * 8][lj] = W_cls[(size_t)i * 256 + j0 + lj];
    }
    __syncthreads();
#pragma unroll
    for (int k = 0; k < 4; ++k) {
      int j = j0 + li + k * 8, i = i0 + lj;
      if (i < CC) WclsT[(size_t)j * CLS_LD + i] = tile[lj][li + k * 8];
    }
  } else {  // Wx 256x128 -> WxT_bf 128x256
    blk -= 1096;  // 0..31
    int i0 = (blk >> 2) * 32, j0 = (blk & 3) * 32;
#pragma unroll
    for (int k = 0; k < 4; ++k)
      tile[li + k * 8][lj] = Wx[(size_t)(i0 + li + k * 8) * 128 + j0 + lj];
    __syncthreads();
#pragma unroll
    for (int k = 0; k < 4; ++k) {
      int j = j0 + li + k * 8;
      WxT_bf[(size_t)j * 256 + i0 + lj] = f2bf(tile[lj][li + k * 8]);
    }
  }
}

// ---------- xW via MFMA bf16: block = 128 rows of [BT,256] x [256,128] ----------
__global__ __launch_bounds__(256) void xw_mfma(
    const float* __restrict__ x, const ushortT* __restrict__ WxT_bf,
    ushortT* __restrict__ x_bf, ushortT* __restrict__ xWT) {
  __shared__ ushortT lds[2 * 128 * 72];  // sX | sW staging; reused as sT[128][136]
#define SX(r, c) lds[(r) * 72 + (c)]
#define SW(r, c) lds[128 * 72 + (r) * 72 + (c)]
#define ST(a, m) lds[(a) * 136 + (m)]
  const int tid = threadIdx.x;
  const int lane = tid & 63, w = tid >> 6;
  const int l15 = lane & 15, quad = lane >> 4;
  const int r0 = blockIdx.x * 128;
  const int bb = blockIdx.x >> 4, t0 = (blockIdx.x & 15) * 128;
  const int row = tid >> 1, half = tid & 1;

  f32x4 acc[2][8];
#pragma unroll
  for (int mt = 0; mt < 2; ++mt)
#pragma unroll
    for (int nt = 0; nt < 8; ++nt) acc[mt][nt] = (f32x4){0.f, 0.f, 0.f, 0.f};

  for (int kk0 = 0; kk0 < 256; kk0 += 64) {
    // stage x (fp32 -> bf16) + write-through to x_bf
    {
      const float4* xp = (const float4*)(x + (size_t)(r0 + row) * DD + kk0 + half * 32);
      uint4 pk[4];
#pragma unroll
      for (int i = 0; i < 4; ++i) {
        float4 f0 = xp[2 * i], f1 = xp[2 * i + 1];
        pk[i].x = (uintT)f2bf(f0.x) | ((uintT)f2bf(f0.y) << 16);
        pk[i].y = (uintT)f2bf(f0.z) | ((uintT)f2bf(f0.w) << 16);
        pk[i].z = (uintT)f2bf(f1.x) | ((uintT)f2bf(f1.y) << 16);
        pk[i].w = (uintT)f2bf(f1.z) | ((uintT)f2bf(f1.w) << 16);
      }
      uint4* sxp = (uint4*)&SX(row, half * 32);
      uint4* gxp = (uint4*)(x_bf + (size_t)(r0 + row) * DD + kk0 + half * 32);
#pragma unroll
      for (int i = 0; i < 4; ++i) { sxp[i] = pk[i]; gxp[i] = pk[i]; }
    }
    // stage WxT_bf slice (n=row)
    {
      const uint4* wp = (const uint4*)(WxT_bf + (size_t)row * DD + kk0 + half * 32);
      uint4* swp = (uint4*)&SW(row, half * 32);
#pragma unroll
      for (int i = 0; i < 4; ++i) swp[i] = wp[i];
    }
    __syncthreads();
#pragma unroll
    for (int kk = 0; kk < 2; ++kk) {
      frag8 a0 = *(const frag8*)&SX(w * 32 + l15, kk * 32 + quad * 8);
      frag8 a1 = *(const frag8*)&SX(w * 32 + 16 + l15, kk * 32 + quad * 8);
#pragma unroll
      for (int nt = 0; nt < 8; ++nt) {
        frag8 bf = *(const frag8*)&SW(nt * 16 + l15, kk * 32 + quad * 8);
        acc[0][nt] = __builtin_amdgcn_mfma_f32_16x16x32_bf16(a0, bf, acc[0][nt], 0, 0, 0);
        acc[1][nt] = __builtin_amdgcn_mfma_f32_16x16x32_bf16(a1, bf, acc[1][nt], 0, 0, 0);
      }
    }
    __syncthreads();
  }
  // transpose-bounce: sT[a][m] = D[m][a], then write xWT[b][a][t0+m]
#pragma unroll
  for (int mt = 0; mt < 2; ++mt)
#pragma unroll
    for (int nt = 0; nt < 8; ++nt)
#pragma unroll
      for (int r = 0; r < 4; ++r) {
        int m = w * 32 + mt * 16 + quad * 4 + r;
        int a = nt * 16 + l15;
        ST(a, m) = f2bf(acc[mt][nt][r]);
      }
  __syncthreads();
  {
    const uint4* sp = (const uint4*)&ST(row, half * 64);
    uint4* gp = (uint4*)(xWT + ((size_t)bb * AA + row) * TT + t0 + half * 64);
#pragma unroll
    for (int i = 0; i < 8; ++i) gp[i] = sp[i];
  }
#undef SX
#undef SW
#undef ST
}

// ---------- fused GRU step v2: ctx/den reduce + gates + h-combine + hWh ----------
// grid 32 (one block per b), 512 thr (8 waves). Gates use the PROVEN round-1
// mapping: 16 lanes cooperate on one weight row (line-level coalesced), 32 rows
// in flight per iteration, 24 iterations for all 768 gate-pairs. Results land
// in LDS; h-combine and hWh run in the same block (no hcomb launch, no global
// gi/gh round-trip).
__global__ __launch_bounds__(512) void gru_kernel(
    const float* __restrict__ ctx_part, const float* __restrict__ den_part,
    const float* __restrict__ W_ih, const float* __restrict__ W_hh,
    const float* __restrict__ b_ih, const float* __restrict__ b_hh,
    const float* __restrict__ Wh, float* __restrict__ hall,
    float* __restrict__ hWh_buf, int s) {
  const int b = blockIdx.x, tid = threadIdx.x;
  __shared__ __align__(16) float sctx[DD];
  __shared__ __align__(16) float sh_prev[HH];
  __shared__ float sgi[768], sgh[768];
  __shared__ __align__(16) float sh[HH];
  __shared__ float part[4][AA];
  __shared__ float sden;
  if (tid < 256) {  // ctx partial reduce (coalesced) + h_prev stage
    float acc = 0.f;
#pragma unroll
    for (int c = 0; c < NCHUNK; ++c)
      acc += ctx_part[((size_t)b * NCHUNK + c) * DD + tid];
    sctx[tid] = acc;  // unscaled; invd applied after the dot
    sh_prev[tid] = (s >= 2) ? hall[((size_t)(s - 2) * BB + b) * HH + tid] : 0.f;
  } else if (tid < 288) {  // den partial reduce on wave 4's low half
    const int l = tid - 256;
    float d = den_part[b * NCHUNK + l];
#pragma unroll
    for (int off = 16; off > 0; off >>= 1) d += __shfl_down(d, off, 32);
    if (l == 0) sden = d;
  }
  __syncthreads();
  const float invd = 1.0f / sden;
  const float4* sctx4 = (const float4*)sctx;
  const float4* shp4 = (const float4*)sh_prev;
  // gates: kq = lane-in-row-team, grp = which row; 32 rows per iteration
  {
    const int kq = tid & 15, grp = tid >> 4;  // grp 0..31
#pragma unroll 2
    for (int it = 0; it < 24; ++it) {
      const int g = it * 32 + grp;  // 0..767
      const float4* wi = (const float4*)(W_ih + (size_t)g * DD) + kq * 4;
      const float4* wh = (const float4*)(W_hh + (size_t)g * HH) + kq * 4;
      float gi = 0.f, gh = 0.f;
#pragma unroll
      for (int j = 0; j < 4; ++j) {
        float4 wv = wi[j], cv = sctx4[kq * 4 + j];
        gi += cv.x * wv.x + cv.y * wv.y + cv.z * wv.z + cv.w * wv.w;
        float4 wv2 = wh[j], hv4 = shp4[kq * 4 + j];
        gh += hv4.x * wv2.x + hv4.y * wv2.y + hv4.z * wv2.z + hv4.w * wv2.w;
      }
#pragma unroll
      for (int off = 8; off > 0; off >>= 1) {
        gi += __shfl_down(gi, off, 16);
        gh += __shfl_down(gh, off, 16);
      }
      if (kq == 0) {
        sgi[g] = gi * invd + b_ih[g];
        sgh[g] = gh + b_hh[g];
      }
    }
  }
  __syncthreads();
  // h-combine (element tid)
  if (tid < 256) {
    float r = sigmoid_fast(sgi[tid] + sgh[tid]);
    float z = sigmoid_fast(sgi[256 + tid] + sgh[256 + tid]);
    float n = tanh_fast(sgi[512 + tid] + r * sgh[512 + tid]);
    float hv = (1.f - z) * n + z * sh_prev[tid];
    hall[((size_t)(s - 1) * BB + b) * HH + tid] = hv;
    sh[tid] = hv;
  }
  __syncthreads();
  // hWh: 128 a x 4-way k-split (64 k each); Wh row fully coalesced across a
  {
    const int a = tid & 127, kh = tid >> 7;  // kh 0..3
    float acc = 0.f;
#pragma unroll 8
    for (int k = kh * 64; k < kh * 64 + 64; ++k)
      acc = fmaf(sh[k], Wh[k * AA + a], acc);
    part[kh][a] = acc;
  }
  __syncthreads();
  if (tid < AA)
    hWh_buf[b * AA + tid] = (part[0][tid] + part[1][tid]) + (part[2][tid] + part[3][tid]);
}

// ---------- per-step attention. grid (32 chunks, 32 b), 256 thr ----------
__global__ __launch_bounds__(256, 4) void att_kernel(
    const ushortT* __restrict__ x_bf, const ushortT* __restrict__ xWT_bf,
    const float* __restrict__ hWh_buf, const float* __restrict__ v,
    float* __restrict__ ctx_part, float* __restrict__ den_part) {
  const int tid = threadIdx.x;
  const int chunk = blockIdx.x;  // 0..31, 64 t's each
  const int b = blockIdx.y;
  const int t0 = chunk * 64;
  __shared__ float sh_hWh[AA], sh_v[AA];
  __shared__ float sh_part[8 * 64];
  __shared__ float sh_w[64];
  __shared__ __align__(16) float sh_ctx[4 * DD];
  if (tid < AA) {
    sh_hWh[tid] = hWh_buf ? hWh_buf[b * AA + tid] : 0.f;
    sh_v[tid] = v[tid];
  }
  // Prefetch Phase-B x into regs (independent of scores) so all loads overlap
  const int j4 = tid >> 6, dq = tid & 63;
  ushort4 xr[16];
  {
    const ushort4* xb4 = (const ushort4*)x_bf;
#pragma unroll
    for (int j = 0; j < 16; ++j)
      xr[j] = xb4[(((size_t)(b * TT + t0 + j * 4 + j4)) * DD >> 2) + dq];
  }
  __syncthreads();
  // Phase A: scores. thread = (q = a-group of 16, tp = t-pair)
  {
    const int q = tid >> 5, tp = tid & 31;
    float p0 = 0.f, p1 = 0.f;
    const ushort2* xw2 = (const ushort2*)xWT_bf;
    const size_t base = (size_t)b * (AA * TT / 2) + (t0 >> 1) + tp;
#pragma unroll
    for (int i = 0; i < 16; ++i) {
      int a = q * 16 + i;
      ushort2 u = xw2[base + (size_t)a * (TT / 2)];
      float hwa = sh_hWh[a], va = sh_v[a];
      p0 = fmaf(tanh_fast(bf2f(u.x) + hwa), va, p0);
      p1 = fmaf(tanh_fast(bf2f(u.y) + hwa), va, p1);
    }
    sh_part[q * 64 + 2 * tp] = p0;
    sh_part[q * 64 + 2 * tp + 1] = p1;
  }
  __syncthreads();
  if (tid < 64) {
    float e = 0.f;
#pragma unroll
    for (int q = 0; q < 8; ++q) e += sh_part[q * 64 + tid];
    sh_w[tid] = __expf(e);  // |e| <= ||v||_1 ~ 5: no overflow, no max-pass
  }
  __syncthreads();
  // Phase B: ctx partials from prefetched regs
  {
    float4 acc = {0.f, 0.f, 0.f, 0.f};
#pragma unroll
    for (int j = 0; j < 16; ++j) {
      float w = sh_w[j * 4 + j4];
      acc.x = fmaf(w, bf2f(xr[j].x), acc.x);
      acc.y = fmaf(w, bf2f(xr[j].y), acc.y);
      acc.z = fmaf(w, bf2f(xr[j].z), acc.z);
      acc.w = fmaf(w, bf2f(xr[j].w), acc.w);
    }
    ((float4*)sh_ctx)[j4 * 64 + dq] = acc;
  }
  __syncthreads();
  {
    float sum = sh_ctx[tid] + sh_ctx[DD + tid] + sh_ctx[2 * DD + tid] + sh_ctx[3 * DD + tid];
    ctx_part[((size_t)b * NCHUNK + chunk) * DD + tid] = sum;  // plain coalesced store
  }
  if (tid < 64) {
    float ds = sh_w[tid];
#pragma unroll
    for (int off = 32; off > 0; off >>= 1) ds += __shfl_down(ds, off, 64);
    if (tid == 0) den_part[b * NCHUNK + chunk] = ds;
  }
}

// ---------- final: out[b,s,c] = hall[s,b,:] @ W_cls^T + b_cls ----------
// LDS-staged WclsT k-panels: kills the 8x redundant L2 reads (one per rg group).
__global__ __launch_bounds__(256) void cls_kernel(
    const float* __restrict__ hall, const float* __restrict__ WclsT,
    const float* __restrict__ b_cls, float* __restrict__ out) {
  const int tid = threadIdx.x;
  const int c0 = blockIdx.x * 128;
  const int r0 = blockIdx.y * 32;
  const int cq = tid & 31, rg = tid >> 5;
  const int c = c0 + cq * 4;
  __shared__ __align__(16) float shh[32 * HH];        // 32 KB: h rows
  __shared__ __align__(16) float sW[CLS_KP][128];     // 16 KB: WclsT k-panel
  {
    const float4* hsrc = (const float4*)(hall + (size_t)r0 * HH);
    float4* hdst = (float4*)shh;
#pragma unroll
    for (int i = 0; i < 8; ++i) hdst[tid + 256 * i] = hsrc[tid + 256 * i];
  }
  float acc[4][4];
#pragma unroll
  for (int j = 0; j < 4; ++j)
#pragma unroll
    for (int l = 0; l < 4; ++l) acc[j][l] = 0.f;
  for (int k0 = 0; k0 < HH; k0 += CLS_KP) {
    __syncthreads();  // prev compute done (and h staged, first iter)
    {   // stage 32k x 128c panel, coalesced, each element once
      const int tk = tid >> 5, tc = tid & 31;
#pragma unroll
      for (int kk = 0; kk < 4; ++kk) {
        int k = tk * 4 + kk;
        ((float4*)&sW[k][0])[tc] =
            *(const float4*)(WclsT + (size_t)(k0 + k) * CLS_LD + c0 + tc * 4);
      }
    }
    __syncthreads();
#pragma unroll
    for (int k4 = 0; k4 < CLS_KP / 4; ++k4) {
      float4 w0 = ((const float4*)&sW[k4 * 4 + 0][0])[cq];
      float4 w1 = ((const float4*)&sW[k4 * 4 + 1][0])[cq];
      float4 w2 = ((const float4*)&sW[k4 * 4 + 2][0])[cq];
      float4 w3 = ((const float4*)&sW[k4 * 4 + 3][0])[cq];
#pragma unroll
      for (int j = 0; j < 4; ++j) {
        float4 h4v = *(const float4*)&shh[(rg * 4 + j) * HH + k0 + k4 * 4];
        acc[j][0] = fmaf(h4v.x, w0.x, acc[j][0]); acc[j][1] = fmaf(h4v.x, w0.y, acc[j][1]);
        acc[j][2] = fmaf(h4v.x, w0.z, acc[j][2]); acc[j][3] = fmaf(h4v.x, w0.w, acc[j][3]);
        acc[j][0] = fmaf(h4v.y, w1.x, acc[j][0]); acc[j][1] = fmaf(h4v.y, w1.y, acc[j][1]);
        acc[j][2] = fmaf(h4v.y, w1.z, acc[j][2]); acc[j][3] = fmaf(h4v.y, w1.w, acc[j][3]);
        acc[j][0] = fmaf(h4v.z, w2.x, acc[j][0]); acc[j][1] = fmaf(h4v.z, w2.y, acc[j][1]);
        acc[j][2] = fmaf(h4v.z, w2.z, acc[j][2]); acc[j][3] = fmaf(h4v.z, w2.w, acc[j][3]);
        acc[j][0] = fmaf(h4v.w, w3.x, acc[j][0]); acc[j][1] = fmaf(h4v.w, w3.y, acc[j][1]);
        acc[j][2] = fmaf(h4v.w, w3.z, acc[j][2]); acc[j][3] = fmaf(h4v.w, w3.w, acc[j][3]);
      }
    }
  }
#pragma unroll
  for (int j = 0; j < 4; ++j) {
    int row = r0 + rg * 4 + j;  // row = s*BB + b
    int bb = row & (BB - 1), st = row >> 5;
    size_t obase = ((size_t)bb * NSTEPS + st) * CC;
#pragma unroll
    for (int l = 0; l < 4; ++l) {
      int cc = c + l;
      if (cc < CC) out[obase + cc] = acc[j][l] + b_cls[cc];
    }
  }
}

extern "C" void kernel_launch(void* const* d_in, const int* in_sizes, int n_in,
                              void* d_out, int out_size, void* d_ws, size_t ws_size,
                              hipStream_t stream) {
  const float* x     = (const float*)d_in[0];
  const float* Wx    = (const float*)d_in[1];
  const float* Wh    = (const float*)d_in[2];
  const float* v     = (const float*)d_in[3];
  const float* W_ih  = (const float*)d_in[4];
  const float* W_hh  = (const float*)d_in[5];
  const float* b_ih  = (const float*)d_in[6];
  const float* b_hh  = (const float*)d_in[7];
  const float* W_cls = (const float*)d_in[8];
  const float* b_cls = (const float*)d_in[9];
  float* out = (float*)d_out;

  // workspace
  float* ctx_part = (float*)d_ws;                           // 32*32*256
  float* den_part = ctx_part + (size_t)BB * NCHUNK * DD;    // 32*32
  float* hWh_buf  = den_part + BB * NCHUNK;                 // 32*128
  float* hall     = hWh_buf + BB * AA;                      // 22*32*256
  float* WclsT    = hall + (size_t)NSTEPS * BB * HH;        // 256*4480
  ushortT* WxT_bf = (ushortT*)(WclsT + (size_t)256 * CLS_LD);  // 128*256
  ushortT* x_bf   = WxT_bf + 128 * 256;                     // BT*256
  ushortT* xWT    = x_bf + (size_t)BB * TT * DD;            // B*A*T

  trans_kernel<<<1096 + 32, 256, 0, stream>>>(Wx, W_cls, WclsT, WxT_bf);
  xw_mfma<<<(BB * TT) / 128, 256, 0, stream>>>(x, WxT_bf, x_bf, xWT);

  att_kernel<<<dim3(NCHUNK, BB), 256, 0, stream>>>(x_bf, xWT, nullptr, v, ctx_part, den_part);
  for (int s = 1; s < NSTEPS; ++s) {
    gru_kernel<<<BB, 512, 0, stream>>>(ctx_part, den_part, W_ih, W_hh,
                                       b_ih, b_hh, Wh, hall, hWh_buf, s);
    att_kernel<<<dim3(NCHUNK, BB), 256, 0, stream>>>(x_bf, xWT, hWh_buf, v, ctx_part, den_part);
  }
  gru_kernel<<<BB, 512, 0, stream>>>(ctx_part, den_part, W_ih, W_hh,
                                     b_ih, b_hh, Wh, hall, hWh_buf, NSTEPS);
  cls_kernel<<<dim3(35, 22), 256, 0, stream>>>(hall, WclsT, b_cls, out);
}

// Round 4
// 724.350 us; speedup vs baseline: 2.3051x; 1.7395x over previous
//
#include <hip/hip_runtime.h>

#define BB 32
#define TT 2048
#define DD 256
#define HH 256
#define AA 128
#define CC 4367
#define CLS_LD 4480   // 35*128, padded WclsT leading dim
#define CLS_KP 32     // cls k-panel staged in LDS
#define NSTEPS 22
#define NCHUNK 32     // att t-chunks (64 t each)

typedef unsigned short ushortT;
typedef unsigned int uintT;
using frag8 = __attribute__((ext_vector_type(8))) short;
using f32x4 = __attribute__((ext_vector_type(4))) float;

__device__ __forceinline__ float tanh_fast(float u) {
  float e = __expf(2.0f * u);
  return 1.0f - 2.0f / (e + 1.0f);
}
__device__ __forceinline__ float sigmoid_fast(float u) {
  return 1.0f / (1.0f + __expf(-u));
}
__device__ __forceinline__ ushortT f2bf(float f) {
  unsigned int u = __float_as_uint(f);
  unsigned int r = (u + 0x7FFFu + ((u >> 16) & 1u)) >> 16;
  return (ushortT)r;
}
__device__ __forceinline__ float bf2f(ushortT v) {
  return __uint_as_float(((unsigned int)v) << 16);
}

// ---------- prep: WclsT fp32 [256][4480] and WxT_bf bf16 [128][256] ----------
__global__ __launch_bounds__(256) void trans_kernel(
    const float* __restrict__ Wx, const float* __restrict__ W_cls,
    float* __restrict__ WclsT, ushortT* __restrict__ WxT_bf) {
  int blk = blockIdx.x;
  __shared__ float tile[32][33];
  const int li = threadIdx.x >> 5, lj = threadIdx.x & 31;
  if (blk < 1096) {  // W_cls 4367x256 -> WclsT 256x4480
    int i0 = (blk >> 3) * 32, j0 = (blk & 7) * 32;
#pragma unroll
    for (int k = 0; k < 4; ++k) {
      int i = i0 + li + k * 8;
      if (i < CC) tile[li + k * 8][lj] = W_cls[(size_t)i * 256 + j0 + lj];
    }
    __syncthreads();
#pragma unroll
    for (int k = 0; k < 4; ++k) {
      int j = j0 + li + k * 8, i = i0 + lj;
      if (i < CC) WclsT[(size_t)j * CLS_LD + i] = tile[lj][li + k * 8];
    }
  } else {  // Wx 256x128 -> WxT_bf 128x256
    blk -= 1096;  // 0..31
    int i0 = (blk >> 2) * 32, j0 = (blk & 3) * 32;
#pragma unroll
    for (int k = 0; k < 4; ++k)
      tile[li + k * 8][lj] = Wx[(size_t)(i0 + li + k * 8) * 128 + j0 + lj];
    __syncthreads();
#pragma unroll
    for (int k = 0; k < 4; ++k) {
      int j = j0 + li + k * 8;
      WxT_bf[(size_t)j * 256 + i0 + lj] = f2bf(tile[lj][li + k * 8]);
    }
  }
}

// ---------- xW via MFMA bf16: block = 128 rows of [BT,256] x [256,128] ----------
__global__ __launch_bounds__(256) void xw_mfma(
    const float* __restrict__ x, const ushortT* __restrict__ WxT_bf,
    ushortT* __restrict__ x_bf, ushortT* __restrict__ xWT) {
  __shared__ ushortT lds[2 * 128 * 72];  // sX | sW staging; reused as sT[128][136]
#define SX(r, c) lds[(r) * 72 + (c)]
#define SW(r, c) lds[128 * 72 + (r) * 72 + (c)]
#define ST(a, m) lds[(a) * 136 + (m)]
  const int tid = threadIdx.x;
  const int lane = tid & 63, w = tid >> 6;
  const int l15 = lane & 15, quad = lane >> 4;
  const int r0 = blockIdx.x * 128;
  const int bb = blockIdx.x >> 4, t0 = (blockIdx.x & 15) * 128;
  const int row = tid >> 1, half = tid & 1;

  f32x4 acc[2][8];
#pragma unroll
  for (int mt = 0; mt < 2; ++mt)
#pragma unroll
    for (int nt = 0; nt < 8; ++nt) acc[mt][nt] = (f32x4){0.f, 0.f, 0.f, 0.f};

  for (int kk0 = 0; kk0 < 256; kk0 += 64) {
    // stage x (fp32 -> bf16) + write-through to x_bf
    {
      const float4* xp = (const float4*)(x + (size_t)(r0 + row) * DD + kk0 + half * 32);
      uint4 pk[4];
#pragma unroll
      for (int i = 0; i < 4; ++i) {
        float4 f0 = xp[2 * i], f1 = xp[2 * i + 1];
        pk[i].x = (uintT)f2bf(f0.x) | ((uintT)f2bf(f0.y) << 16);
        pk[i].y = (uintT)f2bf(f0.z) | ((uintT)f2bf(f0.w) << 16);
        pk[i].z = (uintT)f2bf(f1.x) | ((uintT)f2bf(f1.y) << 16);
        pk[i].w = (uintT)f2bf(f1.z) | ((uintT)f2bf(f1.w) << 16);
      }
      uint4* sxp = (uint4*)&SX(row, half * 32);
      uint4* gxp = (uint4*)(x_bf + (size_t)(r0 + row) * DD + kk0 + half * 32);
#pragma unroll
      for (int i = 0; i < 4; ++i) { sxp[i] = pk[i]; gxp[i] = pk[i]; }
    }
    // stage WxT_bf slice (n=row)
    {
      const uint4* wp = (const uint4*)(WxT_bf + (size_t)row * DD + kk0 + half * 32);
      uint4* swp = (uint4*)&SW(row, half * 32);
#pragma unroll
      for (int i = 0; i < 4; ++i) swp[i] = wp[i];
    }
    __syncthreads();
#pragma unroll
    for (int kk = 0; kk < 2; ++kk) {
      frag8 a0 = *(const frag8*)&SX(w * 32 + l15, kk * 32 + quad * 8);
      frag8 a1 = *(const frag8*)&SX(w * 32 + 16 + l15, kk * 32 + quad * 8);
#pragma unroll
      for (int nt = 0; nt < 8; ++nt) {
        frag8 bf = *(const frag8*)&SW(nt * 16 + l15, kk * 32 + quad * 8);
        acc[0][nt] = __builtin_amdgcn_mfma_f32_16x16x32_bf16(a0, bf, acc[0][nt], 0, 0, 0);
        acc[1][nt] = __builtin_amdgcn_mfma_f32_16x16x32_bf16(a1, bf, acc[1][nt], 0, 0, 0);
      }
    }
    __syncthreads();
  }
  // transpose-bounce: sT[a][m] = D[m][a], then write xWT[b][a][t0+m]
#pragma unroll
  for (int mt = 0; mt < 2; ++mt)
#pragma unroll
    for (int nt = 0; nt < 8; ++nt)
#pragma unroll
      for (int r = 0; r < 4; ++r) {
        int m = w * 32 + mt * 16 + quad * 4 + r;
        int a = nt * 16 + l15;
        ST(a, m) = f2bf(acc[mt][nt][r]);
      }
  __syncthreads();
  {
    const uint4* sp = (const uint4*)&ST(row, half * 64);
    uint4* gp = (uint4*)(xWT + ((size_t)bb * AA + row) * TT + t0 + half * 64);
#pragma unroll
    for (int i = 0; i < 8; ++i) gp[i] = sp[i];
  }
#undef SX
#undef SW
#undef ST
}

// ---------- gates: reduce ctx/den partials, then gi/gh dots (PROVEN round-1) ----------
// grid (12 slices of 64 gates, 32 b), 256 thr. 16 threads per gate (k-split 16),
// coalesced row-segment weight loads, width-16 shfl reduce.
__global__ __launch_bounds__(256) void gates_kernel(
    const float* __restrict__ ctx_part, const float* __restrict__ den_part,
    const float* __restrict__ hall, const float* __restrict__ W_ih,
    const float* __restrict__ W_hh, const float* __restrict__ b_ih,
    const float* __restrict__ b_hh, float* __restrict__ gi_buf,
    float* __restrict__ gh_buf, int s) {
  const int slice = blockIdx.x, b = blockIdx.y, tid = threadIdx.x;
  __shared__ __align__(16) float sctx[DD];
  __shared__ float sden;
  if (tid < 32) {  // reduce den partials (one wave)
    float d = den_part[b * NCHUNK + tid];
#pragma unroll
    for (int off = 16; off > 0; off >>= 1) d += __shfl_down(d, off, 32);
    if (tid == 0) sden = d;
  }
  {  // reduce ctx partials: coalesced (256 lanes x 32 chunks)
    float acc = 0.f;
#pragma unroll
    for (int c = 0; c < NCHUNK; ++c)
      acc += ctx_part[((size_t)b * NCHUNK + c) * DD + tid];
    sctx[tid] = acc;
  }
  __syncthreads();
  const float invd = 1.0f / sden;
  const int kq = tid & 15, gsub = tid >> 4;  // gsub 0..15
  const float4* cp = (const float4*)sctx + kq * 4;
  const float4* hrow = (s >= 2) ? (const float4*)(hall + ((size_t)(s - 2) * BB + b) * HH) + kq * 4 : nullptr;
  float4 c4[4], h4[4];
#pragma unroll
  for (int j = 0; j < 4; ++j) {
    float4 cv = cp[j];
    c4[j].x = cv.x * invd; c4[j].y = cv.y * invd; c4[j].z = cv.z * invd; c4[j].w = cv.w * invd;
    if (hrow) h4[j] = hrow[j];
    else { h4[j].x = 0.f; h4[j].y = 0.f; h4[j].z = 0.f; h4[j].w = 0.f; }
  }
#pragma unroll
  for (int it = 0; it < 4; ++it) {
    const int g = slice * 64 + it * 16 + gsub;
    const float4* wi = (const float4*)(W_ih + (size_t)g * DD) + kq * 4;
    const float4* wh = (const float4*)(W_hh + (size_t)g * HH) + kq * 4;
    float gi = 0.f, gh = 0.f;
#pragma unroll
    for (int j = 0; j < 4; ++j) {
      float4 wv = wi[j];
      gi += c4[j].x * wv.x + c4[j].y * wv.y + c4[j].z * wv.z + c4[j].w * wv.w;
      wv = wh[j];
      gh += h4[j].x * wv.x + h4[j].y * wv.y + h4[j].z * wv.z + h4[j].w * wv.w;
    }
#pragma unroll
    for (int off = 8; off > 0; off >>= 1) {
      gi += __shfl_down(gi, off, 16);
      gh += __shfl_down(gh, off, 16);
    }
    if (kq == 0) {
      gi_buf[b * 768 + g] = gi + b_ih[g];
      gh_buf[b * 768 + g] = gh + b_hh[g];
    }
  }
}

// ---------- h-combine + hWh (PROVEN round-1). grid (32 b, 4 a-slices), 256 thr ----------
__global__ __launch_bounds__(256) void hcomb_kernel(
    const float* __restrict__ gi_buf, const float* __restrict__ gh_buf,
    const float* __restrict__ Wh, float* __restrict__ hall,
    float* __restrict__ hWh_buf, int s) {
  const int b = blockIdx.x, as = blockIdx.y, i = threadIdx.x;
  __shared__ float sh[HH];
  __shared__ float part[8][32];
  {
    float gir = gi_buf[b * 768 + i], giz = gi_buf[b * 768 + 256 + i], gin = gi_buf[b * 768 + 512 + i];
    float ghr = gh_buf[b * 768 + i], ghz = gh_buf[b * 768 + 256 + i], ghn = gh_buf[b * 768 + 512 + i];
    float hp = (s >= 2) ? hall[((size_t)(s - 2) * BB + b) * HH + i] : 0.f;
    float r = sigmoid_fast(gir + ghr);
    float z = sigmoid_fast(giz + ghz);
    float n = tanh_fast(gin + r * ghn);
    float hv = (1.f - z) * n + z * hp;
    if (as == 0) hall[((size_t)(s - 1) * BB + b) * HH + i] = hv;
    sh[i] = hv;
  }
  __syncthreads();
  {
    const int a = i & 31, kq = i >> 5;
    const int ga = as * 32 + a;
    float acc = 0.f;
#pragma unroll
    for (int k = kq * 32; k < kq * 32 + 32; ++k)
      acc = fmaf(sh[k], Wh[k * AA + ga], acc);
    part[kq][a] = acc;
  }
  __syncthreads();
  if (i < 32) {
    float sum = part[0][i] + part[1][i] + part[2][i] + part[3][i]
              + part[4][i] + part[5][i] + part[6][i] + part[7][i];
    hWh_buf[b * AA + as * 32 + i] = sum;
  }
}

// ---------- per-step attention. grid (32 chunks, 32 b), 256 thr ----------
__global__ __launch_bounds__(256, 4) void att_kernel(
    const ushortT* __restrict__ x_bf, const ushortT* __restrict__ xWT_bf,
    const float* __restrict__ hWh_buf, const float* __restrict__ v,
    float* __restrict__ ctx_part, float* __restrict__ den_part) {
  const int tid = threadIdx.x;
  const int chunk = blockIdx.x;  // 0..31, 64 t's each
  const int b = blockIdx.y;
  const int t0 = chunk * 64;
  __shared__ float sh_hWh[AA], sh_v[AA];
  __shared__ float sh_part[8 * 64];
  __shared__ float sh_w[64];
  __shared__ __align__(16) float sh_ctx[4 * DD];
  if (tid < AA) {
    sh_hWh[tid] = hWh_buf ? hWh_buf[b * AA + tid] : 0.f;
    sh_v[tid] = v[tid];
  }
  // Prefetch Phase-B x into regs (independent of scores) so all loads overlap
  const int j4 = tid >> 6, dq = tid & 63;
  ushort4 xr[16];
  {
    const ushort4* xb4 = (const ushort4*)x_bf;
#pragma unroll
    for (int j = 0; j < 16; ++j)
      xr[j] = xb4[(((size_t)(b * TT + t0 + j * 4 + j4)) * DD >> 2) + dq];
  }
  __syncthreads();
  // Phase A: scores. thread = (q = a-group of 16, tp = t-pair)
  {
    const int q = tid >> 5, tp = tid & 31;
    float p0 = 0.f, p1 = 0.f;
    const ushort2* xw2 = (const ushort2*)xWT_bf;
    const size_t base = (size_t)b * (AA * TT / 2) + (t0 >> 1) + tp;
#pragma unroll
    for (int i = 0; i < 16; ++i) {
      int a = q * 16 + i;
      ushort2 u = xw2[base + (size_t)a * (TT / 2)];
      float hwa = sh_hWh[a], va = sh_v[a];
      p0 = fmaf(tanh_fast(bf2f(u.x) + hwa), va, p0);
      p1 = fmaf(tanh_fast(bf2f(u.y) + hwa), va, p1);
    }
    sh_part[q * 64 + 2 * tp] = p0;
    sh_part[q * 64 + 2 * tp + 1] = p1;
  }
  __syncthreads();
  if (tid < 64) {
    float e = 0.f;
#pragma unroll
    for (int q = 0; q < 8; ++q) e += sh_part[q * 64 + tid];
    sh_w[tid] = __expf(e);  // |e| <= ||v||_1 ~ 5: no overflow, no max-pass
  }
  __syncthreads();
  // Phase B: ctx partials from prefetched regs
  {
    float4 acc = {0.f, 0.f, 0.f, 0.f};
#pragma unroll
    for (int j = 0; j < 16; ++j) {
      float w = sh_w[j * 4 + j4];
      acc.x = fmaf(w, bf2f(xr[j].x), acc.x);
      acc.y = fmaf(w, bf2f(xr[j].y), acc.y);
      acc.z = fmaf(w, bf2f(xr[j].z), acc.z);
      acc.w = fmaf(w, bf2f(xr[j].w), acc.w);
    }
    ((float4*)sh_ctx)[j4 * 64 + dq] = acc;
  }
  __syncthreads();
  {
    float sum = sh_ctx[tid] + sh_ctx[DD + tid] + sh_ctx[2 * DD + tid] + sh_ctx[3 * DD + tid];
    ctx_part[((size_t)b * NCHUNK + chunk) * DD + tid] = sum;  // plain coalesced store
  }
  if (tid < 64) {
    float ds = sh_w[tid];
#pragma unroll
    for (int off = 32; off > 0; off >>= 1) ds += __shfl_down(ds, off, 64);
    if (tid == 0) den_part[b * NCHUNK + chunk] = ds;
  }
}

// ---------- final: out[b,s,c] = hall[s,b,:] @ W_cls^T + b_cls ----------
// LDS-staged WclsT k-panels: kills the 8x redundant L2 reads (one per rg group).
__global__ __launch_bounds__(256) void cls_kernel(
    const float* __restrict__ hall, const float* __restrict__ WclsT,
    const float* __restrict__ b_cls, float* __restrict__ out) {
  const int tid = threadIdx.x;
  const int c0 = blockIdx.x * 128;
  const int r0 = blockIdx.y * 32;
  const int cq = tid & 31, rg = tid >> 5;
  const int c = c0 + cq * 4;
  __shared__ __align__(16) float shh[32 * HH];        // 32 KB: h rows
  __shared__ __align__(16) float sW[CLS_KP][128];     // 16 KB: WclsT k-panel
  {
    const float4* hsrc = (const float4*)(hall + (size_t)r0 * HH);
    float4* hdst = (float4*)shh;
#pragma unroll
    for (int i = 0; i < 8; ++i) hdst[tid + 256 * i] = hsrc[tid + 256 * i];
  }
  float acc[4][4];
#pragma unroll
  for (int j = 0; j < 4; ++j)
#pragma unroll
    for (int l = 0; l < 4; ++l) acc[j][l] = 0.f;
  for (int k0 = 0; k0 < HH; k0 += CLS_KP) {
    __syncthreads();  // prev compute done (and h staged, first iter)
    {   // stage 32k x 128c panel, coalesced, each element once
      const int tk = tid >> 5, tc = tid & 31;
#pragma unroll
      for (int kk = 0; kk < 4; ++kk) {
        int k = tk * 4 + kk;
        ((float4*)&sW[k][0])[tc] =
            *(const float4*)(WclsT + (size_t)(k0 + k) * CLS_LD + c0 + tc * 4);
      }
    }
    __syncthreads();
#pragma unroll
    for (int k4 = 0; k4 < CLS_KP / 4; ++k4) {
      float4 w0 = ((const float4*)&sW[k4 * 4 + 0][0])[cq];
      float4 w1 = ((const float4*)&sW[k4 * 4 + 1][0])[cq];
      float4 w2 = ((const float4*)&sW[k4 * 4 + 2][0])[cq];
      float4 w3 = ((const float4*)&sW[k4 * 4 + 3][0])[cq];
#pragma unroll
      for (int j = 0; j < 4; ++j) {
        float4 h4v = *(const float4*)&shh[(rg * 4 + j) * HH + k0 + k4 * 4];
        acc[j][0] = fmaf(h4v.x, w0.x, acc[j][0]); acc[j][1] = fmaf(h4v.x, w0.y, acc[j][1]);
        acc[j][2] = fmaf(h4v.x, w0.z, acc[j][2]); acc[j][3] = fmaf(h4v.x, w0.w, acc[j][3]);
        acc[j][0] = fmaf(h4v.y, w1.x, acc[j][0]); acc[j][1] = fmaf(h4v.y, w1.y, acc[j][1]);
        acc[j][2] = fmaf(h4v.y, w1.z, acc[j][2]); acc[j][3] = fmaf(h4v.y, w1.w, acc[j][3]);
        acc[j][0] = fmaf(h4v.z, w2.x, acc[j][0]); acc[j][1] = fmaf(h4v.z, w2.y, acc[j][1]);
        acc[j][2] = fmaf(h4v.z, w2.z, acc[j][2]); acc[j][3] = fmaf(h4v.z, w2.w, acc[j][3]);
        acc[j][0] = fmaf(h4v.w, w3.x, acc[j][0]); acc[j][1] = fmaf(h4v.w, w3.y, acc[j][1]);
        acc[j][2] = fmaf(h4v.w, w3.z, acc[j][2]); acc[j][3] = fmaf(h4v.w, w3.w, acc[j][3]);
      }
    }
  }
#pragma unroll
  for (int j = 0; j < 4; ++j) {
    int row = r0 + rg * 4 + j;  // row = s*BB + b
    int bb = row & (BB - 1), st = row >> 5;
    size_t obase = ((size_t)bb * NSTEPS + st) * CC;
#pragma unroll
    for (int l = 0; l < 4; ++l) {
      int cc = c + l;
      if (cc < CC) out[obase + cc] = acc[j][l] + b_cls[cc];
    }
  }
}

extern "C" void kernel_launch(void* const* d_in, const int* in_sizes, int n_in,
                              void* d_out, int out_size, void* d_ws, size_t ws_size,
                              hipStream_t stream) {
  const float* x     = (const float*)d_in[0];
  const float* Wx    = (const float*)d_in[1];
  const float* Wh    = (const float*)d_in[2];
  const float* v     = (const float*)d_in[3];
  const float* W_ih  = (const float*)d_in[4];
  const float* W_hh  = (const float*)d_in[5];
  const float* b_ih  = (const float*)d_in[6];
  const float* b_hh  = (const float*)d_in[7];
  const float* W_cls = (const float*)d_in[8];
  const float* b_cls = (const float*)d_in[9];
  float* out = (float*)d_out;

  // workspace
  float* ctx_part = (float*)d_ws;                           // 32*32*256
  float* den_part = ctx_part + (size_t)BB * NCHUNK * DD;    // 32*32
  float* hWh_buf  = den_part + BB * NCHUNK;                 // 32*128
  float* gi_buf   = hWh_buf + BB * AA;                      // 32*768
  float* gh_buf   = gi_buf + BB * 768;                      // 32*768
  float* hall     = gh_buf + BB * 768;                      // 22*32*256
  float* WclsT    = hall + (size_t)NSTEPS * BB * HH;        // 256*4480
  ushortT* WxT_bf = (ushortT*)(WclsT + (size_t)256 * CLS_LD);  // 128*256
  ushortT* x_bf   = WxT_bf + 128 * 256;                     // BT*256
  ushortT* xWT    = x_bf + (size_t)BB * TT * DD;            // B*A*T

  trans_kernel<<<1096 + 32, 256, 0, stream>>>(Wx, W_cls, WclsT, WxT_bf);
  xw_mfma<<<(BB * TT) / 128, 256, 0, stream>>>(x, WxT_bf, x_bf, xWT);

  att_kernel<<<dim3(NCHUNK, BB), 256, 0, stream>>>(x_bf, xWT, nullptr, v, ctx_part, den_part);
  for (int s = 1; s < NSTEPS; ++s) {
    gates_kernel<<<dim3(12, BB), 256, 0, stream>>>(ctx_part, den_part, hall, W_ih, W_hh,
                                                   b_ih, b_hh, gi_buf, gh_buf, s);
    hcomb_kernel<<<dim3(BB, 4), 256, 0, stream>>>(gi_buf, gh_buf, Wh, hall, hWh_buf, s);
    att_kernel<<<dim3(NCHUNK, BB), 256, 0, stream>>>(x_bf, xWT, hWh_buf, v, ctx_part, den_part);
  }
  gates_kernel<<<dim3(12, BB), 256, 0, stream>>>(ctx_part, den_part, hall, W_ih, W_hh,
                                                 b_ih, b_hh, gi_buf, gh_buf, NSTEPS);
  hcomb_kernel<<<dim3(BB, 4), 256, 0, stream>>>(gi_buf, gh_buf, Wh, hall, hWh_buf, NSTEPS);
  cls_kernel<<<dim3(35, 22), 256, 0, stream>>>(hall, WclsT, b_cls, out);
}